// Round 6
// baseline (360.502 us; speedup 1.0000x reference)
//
#include <hip/hip_runtime.h>

#define CH    200
#define NE    8
#define OUTC  (CH - NE + 1)   // 193
#define HW    (128 * 128)     // 16384
#define VEC   4
#define THREADS 256
#define NCHUNKS 4             // chunks of {48,48,48,49} out-channels

// 3-bank register pipeline, rotation by POSITION (no mov rotation):
// six straight-line group calls cycle the bank roles (A,B,C)->(B,C,A)->...
// Each group: issue 8 loads for ch c+16..c+23 into L, then 8 outputs from
// R0 (ch c..c+7) and R1 (ch c+8..c+15). First use of a bank's loads is two
// groups after issue -> ~2 groups of FMA slack per load, 8-16 loads in
// flight per wave. All indices compile-time (rule #20).
// __launch_bounds__(256,4): cap VGPR at 128 -> 4 waves/SIMD -> 4 blocks/CU
// -> the 1024-block grid is a single resident shift (no 768+256 imbalance).

typedef float f32x4 __attribute__((ext_vector_type(4)));

__device__ __forceinline__ void fma4(f32x4& a, float s, f32x4 v) {
  a[0] += s * v[0]; a[1] += s * v[1]; a[2] += s * v[2]; a[3] += s * v[3];
}

// Outputs c..c+7 from R0 (ch c..c+7) + R1 (ch c+8..c+15); optionally
// prefetch ch c+16..c+23 into L. No clamping needed: the last group of
// each chunk is called with PRELOAD=false, so channel indices never
// exceed c0+55 <= 199.
template <bool PRELOAD>
__device__ __forceinline__ void do_group(
    int c, const float* __restrict__ xp, float* __restrict__ op,
    const float* sW, const float* sb,
    const f32x4 (&R0)[8], const f32x4 (&R1)[8], f32x4 (&L)[8]) {
  if (PRELOAD) {
#pragma unroll
    for (int k = 0; k < 8; ++k)
      L[k] = *(const f32x4*)(xp + (size_t)(c + 16 + k) * HW);
  }
#pragma unroll
  for (int j = 0; j < 8; ++j) {
    const int cc = c + j;
    const f32x4 w0 = *(const f32x4*)&sW[cc * NE];
    const f32x4 w1 = *(const f32x4*)&sW[cc * NE + 4];
    const float bb = sb[cc];
    f32x4 acc = {bb, bb, bb, bb};
#pragma unroll
    for (int k = 0; k < 8; ++k) {
      const int idx = j + k;                    // compile-time, 0..14
      const f32x4 v = (idx < 8) ? R0[idx & 7] : R1[idx & 7];
      const float w = (k < 4) ? w0[k] : w1[k - 4];
      fma4(acc, w, v);
    }
    // out is write-once: non-temporal keeps L2/L3 for x.
    __builtin_nontemporal_store(acc, (f32x4*)(op + (size_t)cc * HW));
  }
}

__global__ __launch_bounds__(THREADS, 4) void neigh_conv_kernel(
    const float* __restrict__ x, const float* __restrict__ W,
    const float* __restrict__ b, float* __restrict__ out) {
  __shared__ __align__(16) float sW[OUTC * NE];
  __shared__ float sb[OUTC];
  for (int i = threadIdx.x; i < OUTC * NE; i += THREADS) sW[i] = W[i];
  for (int i = threadIdx.x; i < OUTC; i += THREADS) sb[i] = b[i];
  __syncthreads();

  const int pos   = (blockIdx.x * THREADS + threadIdx.x) * VEC;
  const int n     = blockIdx.y;
  const int chunk = blockIdx.z;
  const int c0 = (chunk * OUTC) / NCHUNKS;        // 0,48,96,144
  const int c1 = ((chunk + 1) * OUTC) / NCHUNKS;  // 48,96,144,193

  const float* xp = x + (size_t)n * CH * HW + pos;
  float* op       = out + (size_t)n * OUTC * HW + pos;

  f32x4 A[8], B[8], C[8];
  // Prologue: A = ch c0..c0+7, B = ch c0+8..c0+15 (16 loads in flight).
#pragma unroll
  for (int k = 0; k < 8; ++k)
    A[k] = *(const f32x4*)(xp + (size_t)(c0 + k) * HW);
#pragma unroll
  for (int k = 0; k < 8; ++k)
    B[k] = *(const f32x4*)(xp + (size_t)(c0 + 8 + k) * HW);

  int c = c0;
  do_group<true >(c, xp, op, sW, sb, A, B, C); c += 8;  // loads C: c0+16..23
  do_group<true >(c, xp, op, sW, sb, B, C, A); c += 8;  // loads A: c0+24..31
  do_group<true >(c, xp, op, sW, sb, C, A, B); c += 8;  // loads B: c0+32..39
  do_group<true >(c, xp, op, sW, sb, A, B, C); c += 8;  // loads C: c0+40..47
  do_group<true >(c, xp, op, sW, sb, B, C, A); c += 8;  // loads A: c0+48..55
  do_group<false>(c, xp, op, sW, sb, C, A, B); c += 8;  // no prefetch
  // Bank contents now: A = ch c0+48..c0+55.

  // Tail: only chunk 3 (c1-c0 = 49). Output 192 needs ch 192..199 = A.
  if (c < c1) {
    const f32x4 w0 = *(const f32x4*)&sW[c * NE];
    const f32x4 w1 = *(const f32x4*)&sW[c * NE + 4];
    const float bb = sb[c];
    f32x4 acc = {bb, bb, bb, bb};
#pragma unroll
    for (int k = 0; k < 8; ++k) {
      const float w = (k < 4) ? w0[k] : w1[k - 4];
      fma4(acc, w, A[k]);
    }
    __builtin_nontemporal_store(acc, (f32x4*)(op + (size_t)c * HW));
  }
}

extern "C" void kernel_launch(void* const* d_in, const int* in_sizes, int n_in,
                              void* d_out, int out_size, void* d_ws, size_t ws_size,
                              hipStream_t stream) {
  const float* x = (const float*)d_in[0];
  const float* W = (const float*)d_in[1];
  const float* b = (const float*)d_in[2];
  float* out = (float*)d_out;

  // Fixed problem shape: x = (16, 200, 128, 128) f32.
  const int N = 16;

  dim3 grid(HW / VEC / THREADS /*16*/, N, NCHUNKS);
  neigh_conv_kernel<<<grid, THREADS, 0, stream>>>(x, W, b, out);
}